// Round 1
// baseline (573.701 us; speedup 1.0000x reference)
//
#include <hip/hip_runtime.h>
#include <math.h>

// VocosISTFTHead on MI355X.
// Pipeline:
//  K1 gemm_coeffs : spec = hs @ W.T + b, fused epilogue -> complex coeffs
//                   C[k] = min(exp(spec_mag),100) * (cos(phase), sin(phase)),
//                   imag zeroed at DC (k=0) and Nyquist (k=512) to match irfft.
//  K2 fft_win     : per frame, 1024-pt real iFFT via 512-pt complex Stockham
//                   radix-8 iFFT (pack trick), multiply by Hann window.
//  K3 gather_out  : deterministic overlap-add gather + window^2 normalization.
// ws usage: one buffer of 32768 rows x 1028 floats (134.7 MB), reused in place.

#define RS      1028          // row stride (floats) for coeffs/frames buffer
#define FRAMES  32768         // B*T = 16*2048
#define TWO_PI  6.283185307179586f

__device__ __forceinline__ float2 f2(float x, float y){ return make_float2(x,y); }
__device__ __forceinline__ float2 cadd(float2 a, float2 b){ return f2(a.x+b.x, a.y+b.y); }
__device__ __forceinline__ float2 csub(float2 a, float2 b){ return f2(a.x-b.x, a.y-b.y); }
__device__ __forceinline__ float2 cmul(float2 a, float2 b){ return f2(a.x*b.x - a.y*b.y, a.x*b.y + a.y*b.x); }

// ---------------------------------------------------------------------------
// K1: f32 tiled GEMM (BM=128 rows x 64 mag/phase column-pairs), 256 threads.
// Each thread: 8 rows x 4 pairs -> 64 accumulators (mag) + 64 (phase)? No:
// 8x4 mag + 8x4 phase = 64 f32 acc total.
// ---------------------------------------------------------------------------
__global__ __launch_bounds__(256) void gemm_coeffs(
    const float* __restrict__ hs, const float* __restrict__ Wm,
    const float* __restrict__ bias, float* __restrict__ coeffs)
{
  __shared__ float As[16][128];       // A tile transposed: As[k][m]
  __shared__ float Bs[2][16][64];     // Bs[0]=mag rows, Bs[1]=phase rows: [k][c]
  const int tid = threadIdx.x;
  const int m0 = blockIdx.x * 128;
  const int p0 = blockIdx.y * 64;
  const int tx = tid & 15, ty = tid >> 4;

  float accm[8][4], accp[8][4];
  #pragma unroll
  for (int i = 0; i < 8; ++i)
    #pragma unroll
    for (int j = 0; j < 4; ++j) { accm[i][j] = 0.f; accp[i][j] = 0.f; }

  for (int kt = 0; kt < 32; ++kt) {
    const int k0 = kt * 16;
    // A tile 128x16 = 512 float4
    #pragma unroll
    for (int h = 0; h < 2; ++h) {
      const int fi = tid + h * 256;
      const int r  = fi >> 2;
      const int c4 = (fi & 3) * 4;
      const float4 v = *(const float4*)(hs + (size_t)(m0 + r) * 512 + k0 + c4);
      As[c4+0][r] = v.x; As[c4+1][r] = v.y; As[c4+2][r] = v.z; As[c4+3][r] = v.w;
    }
    // B tiles 2 x (64x16) = 512 float4
    #pragma unroll
    for (int h = 0; h < 2; ++h) {
      const int fi   = tid + h * 256;
      const int part = fi >> 8;
      const int wi   = fi & 255;
      const int rr   = wi >> 2;
      const int c4   = (wi & 3) * 4;
      float4 v = make_float4(0.f, 0.f, 0.f, 0.f);
      const int prow = p0 + rr;
      if (prow < 513) {
        const int row = part ? (513 + prow) : prow;
        v = *(const float4*)(Wm + (size_t)row * 512 + k0 + c4);
      }
      Bs[part][c4+0][rr] = v.x; Bs[part][c4+1][rr] = v.y;
      Bs[part][c4+2][rr] = v.z; Bs[part][c4+3][rr] = v.w;
    }
    __syncthreads();
    #pragma unroll
    for (int k = 0; k < 16; ++k) {
      const float4 A0 = *(const float4*)&As[k][ty*8];
      const float4 A1 = *(const float4*)&As[k][ty*8+4];
      const float4 Bm = *(const float4*)&Bs[0][k][tx*4];
      const float4 Bp = *(const float4*)&Bs[1][k][tx*4];
      const float am[8] = {A0.x,A0.y,A0.z,A0.w,A1.x,A1.y,A1.z,A1.w};
      const float bm[4] = {Bm.x,Bm.y,Bm.z,Bm.w};
      const float bp[4] = {Bp.x,Bp.y,Bp.z,Bp.w};
      #pragma unroll
      for (int i = 0; i < 8; ++i) {
        #pragma unroll
        for (int j = 0; j < 4; ++j) {
          accm[i][j] = fmaf(am[i], bm[j], accm[i][j]);
          accp[i][j] = fmaf(am[i], bp[j], accp[i][j]);
        }
      }
    }
    __syncthreads();
  }

  // Epilogue: spec -> complex coefficient, write interleaved (a,b) pairs.
  const int cbase = p0 + tx * 4;
  float bm4[4], bp4[4];
  #pragma unroll
  for (int j = 0; j < 4; ++j) {
    const int c = cbase + j;
    bm4[j] = (c < 513) ? bias[c]       : 0.f;
    bp4[j] = (c < 513) ? bias[513 + c] : 0.f;
  }
  #pragma unroll
  for (int i = 0; i < 8; ++i) {
    const int fidx = m0 + ty * 8 + i;
    float o8[8];
    #pragma unroll
    for (int j = 0; j < 4; ++j) {
      const int c = cbase + j;
      const float sm = accm[i][j] + bm4[j];
      const float sp = accp[i][j] + bp4[j];
      const float mag = fminf(expf(sm), 100.0f);
      float aa = mag * cosf(sp);
      float bb = mag * sinf(sp);
      if (c == 0 || c == 512) bb = 0.f;   // irfft ignores imag at DC/Nyquist
      o8[2*j] = aa; o8[2*j+1] = bb;
    }
    float* dst = coeffs + (size_t)fidx * RS + 2 * cbase;
    if (cbase + 3 < 513) {
      *(float4*)(dst)     = make_float4(o8[0], o8[1], o8[2], o8[3]);
      *(float4*)(dst + 4) = make_float4(o8[4], o8[5], o8[6], o8[7]);
    } else {
      #pragma unroll
      for (int j = 0; j < 4; ++j)
        if (cbase + j < 513) { dst[2*j] = o8[2*j]; dst[2*j+1] = o8[2*j+1]; }
    }
  }
}

// ---------------------------------------------------------------------------
// K2: per-frame irfft(1024) + window. One wave (64 lanes) per frame, 4 frames
// per 256-thread block. 512-pt complex inverse FFT = 3 Stockham radix-8
// stages, LDS ping-pong with pad index s+(s>>3) to break transpose conflicts.
// ---------------------------------------------------------------------------
#define PIDX(s) ((s) + ((s) >> 3))

template<int NS>
__device__ __forceinline__ void stage(const float2* in, float2* out, int l)
{
  float2 v[8];
  #pragma unroll
  for (int r = 0; r < 8; ++r) v[r] = in[PIDX(l + 64*r)];
  if (NS > 1) {
    const float ang = TWO_PI * (float)(l & (NS-1)) / (float)(NS * 8);
    float sn, cs; __sincosf(ang, &sn, &cs);
    const float2 wb = f2(cs, sn);
    float2 cur = wb;
    #pragma unroll
    for (int r = 1; r < 8; ++r) { v[r] = cmul(v[r], cur); cur = cmul(cur, wb); }
  }
  // 8-point DFT, sign = +1 (inverse)
  const float2 e0=v[0], e1=v[2], e2=v[4], e3=v[6];
  const float2 o0=v[1], o1=v[3], o2=v[5], o3=v[7];
  float2 a = cadd(e0,e2), b = csub(e0,e2), c = cadd(e1,e3), d = csub(e1,e3);
  const float2 E0 = cadd(a,c), E2 = csub(a,c);
  const float2 E1 = f2(b.x - d.y, b.y + d.x), E3 = f2(b.x + d.y, b.y - d.x);
  a = cadd(o0,o2); b = csub(o0,o2); c = cadd(o1,o3); d = csub(o1,o3);
  const float2 O0 = cadd(a,c), O2 = csub(a,c);
  const float2 O1 = f2(b.x - d.y, b.y + d.x), O3 = f2(b.x + d.y, b.y - d.x);
  const float r2 = 0.70710678118654752f;
  const float2 t0 = O0;
  const float2 t1 = f2(r2*(O1.x - O1.y),  r2*(O1.x + O1.y));
  const float2 t2 = f2(-O2.y, O2.x);
  const float2 t3 = f2(-r2*(O3.x + O3.y), r2*(O3.x - O3.y));
  float2 X[8];
  X[0]=cadd(E0,t0); X[4]=csub(E0,t0);
  X[1]=cadd(E1,t1); X[5]=csub(E1,t1);
  X[2]=cadd(E2,t2); X[6]=csub(E2,t2);
  X[3]=cadd(E3,t3); X[7]=csub(E3,t3);
  const int idxD = (l / NS) * (NS * 8) + (l & (NS-1));
  #pragma unroll
  for (int q = 0; q < 8; ++q) out[PIDX(idxD + q*NS)] = X[q];
}

__global__ __launch_bounds__(256) void fft_win(
    const float* coeffs, float* frames, const float* __restrict__ window)
{
  __shared__ float2 bA[4][576];
  __shared__ float2 bB[4][576];
  const int tid = threadIdx.x;
  const int w = tid >> 6, l = tid & 63;
  const size_t f = (size_t)blockIdx.x * 4 + w;
  const float* crow = coeffs + f * RS;
  const float sc = 1.0f / 1024.0f;
  const float a512 = crow[1024];

  // Pack: G[k] = E + iO (scaled by 1/1024), E = s(Xk + X_{k+512}),
  // O = s * w_k * (Xk - X_{k+512}), w_k = e^{+2pi i k/1024};
  // partner G[512-k] = (Ex+Oy, Ox-Ey) derived via conjugate symmetry.
  #pragma unroll
  for (int j = 0; j < 4; ++j) {
    const int k = 1 + l + 64*j;                 // 1..256
    const float2 Ck = *(const float2*)(crow + 2*k);
    const float2 Cq = *(const float2*)(crow + 2*(512-k));
    float sn, cs; __sincosf(TWO_PI * (1.0f/1024.0f) * (float)k, &sn, &cs);
    const float Ex = sc*(Ck.x + Cq.x), Ey = sc*(Ck.y - Cq.y);
    const float Dx = Ck.x - Cq.x,      Dy = Ck.y + Cq.y;
    const float Ox = sc*(cs*Dx - sn*Dy), Oy = sc*(cs*Dy + sn*Dx);
    bA[w][PIDX(k)]     = f2(Ex - Oy, Ey + Ox);
    bA[w][PIDX(512-k)] = f2(Ex + Oy, Ox - Ey);
  }
  if (l == 0) {
    const float a0 = crow[0];
    bA[w][PIDX(0)] = f2(sc*(a0 + a512), sc*(a0 - a512));
  }
  __syncthreads();
  stage<1 >(bA[w], bB[w], l);
  __syncthreads();
  stage<8 >(bB[w], bA[w], l);
  __syncthreads();
  stage<64>(bA[w], bB[w], l);
  __syncthreads();

  // z[m] = x[2m] + i x[2m+1]; apply window, store.
  float* frow = frames + f * RS;
  #pragma unroll
  for (int j = 0; j < 8; ++j) {
    const int m = l + 64*j;
    const float2 z  = bB[w][PIDX(m)];
    const float2 wv = *(const float2*)(window + 2*m);
    *(float2*)(frow + 2*m) = f2(z.x * wv.x, z.y * wv.y);
  }
}

// ---------------------------------------------------------------------------
// K3: overlap-add gather + normalization. One thread per output sample.
// out[b][jj] = sum_t frames[b,t, s-256t] / sum_t window[s-256t]^2, s = jj+384.
// ---------------------------------------------------------------------------
__global__ __launch_bounds__(256) void gather_out(
    const float* __restrict__ frames, const float* __restrict__ window,
    float* __restrict__ out)
{
  const int idx = blockIdx.x * 256 + threadIdx.x;   // 8,388,608 total
  const int b  = idx >> 19;
  const int jj = idx & 524287;
  const int s  = jj + 384;
  int tlo = (s - 768) >> 8; if (tlo < 0) tlo = 0;     // ceil((s-1023)/256)
  int thi = s >> 8;         if (thi > 2047) thi = 2047;
  float acc = 0.f, nrm = 0.f;
  for (int t = tlo; t <= thi; ++t) {
    const int n = s - (t << 8);
    const float wv = window[n];
    nrm = fmaf(wv, wv, nrm);
    acc += frames[(size_t)(b * 2048 + t) * RS + n];
  }
  out[idx] = acc / nrm;
}

// ---------------------------------------------------------------------------
extern "C" void kernel_launch(void* const* d_in, const int* in_sizes, int n_in,
                              void* d_out, int out_size, void* d_ws, size_t ws_size,
                              hipStream_t stream)
{
  const float* hs     = (const float*)d_in[0];   // (16,2048,512)
  const float* Wm     = (const float*)d_in[1];   // (1026,512)
  const float* bias   = (const float*)d_in[2];   // (1026,)
  const float* window = (const float*)d_in[3];   // (1024,)
  float* buf = (float*)d_ws;                     // 32768 x 1028 floats

  dim3 gg(FRAMES / 128, 9);                      // 256 x 9 blocks
  gemm_coeffs<<<gg, 256, 0, stream>>>(hs, Wm, bias, buf);
  fft_win<<<FRAMES / 4, 256, 0, stream>>>(buf, buf, window);
  gather_out<<<8388608 / 256, 256, 0, stream>>>(buf, window, (float*)d_out);
}

// Round 2
// 216.914 us; speedup vs baseline: 2.6448x; 2.6448x over previous
//
#include <hip/hip_runtime.h>
#include <math.h>
#include <stdint.h>

// VocosISTFTHead on MI355X.
//  K0 convert_B  : W (1026x512 f32) -> block-tiled bf16 hi/lo planes (split precision)
//  K1 gemm_mfma  : spec = hs @ W.T + b via bf16-split MFMA (Ah*Bh + Al*Bh + Ah*Bl),
//                  fused epilogue -> complex coeffs (exp/clamp, cos/sin)
//  K2 fft_win    : 1024-pt real iFFT per frame (512-pt complex Stockham radix-8) * window
//  K3 gather_out : deterministic overlap-add gather + window^2 normalization
// ws: coeffs/frames 32768x1028 f32 (134.7MB) | Bhi 1.125MB | Blo 1.125MB

#define RS      1028
#define FRAMES  32768
#define TWO_PI  6.283185307179586f

typedef unsigned short ushort_t;
typedef __attribute__((ext_vector_type(8)))  short bf16x8;
typedef __attribute__((ext_vector_type(16))) float f32x16;

#define GLDS(gp, lp) __builtin_amdgcn_global_load_lds( \
    (const __attribute__((address_space(1))) void*)(gp), \
    (__attribute__((address_space(3))) void*)(lp), 16, 0, 0)

__device__ __forceinline__ float2 f2(float x, float y){ return make_float2(x,y); }
__device__ __forceinline__ float2 cadd(float2 a, float2 b){ return f2(a.x+b.x, a.y+b.y); }
__device__ __forceinline__ float2 csub(float2 a, float2 b){ return f2(a.x-b.x, a.y-b.y); }
__device__ __forceinline__ float2 cmul(float2 a, float2 b){ return f2(a.x*b.x - a.y*b.y, a.x*b.y + a.y*b.x); }

// ---------------------------------------------------------------------------
// K0: W -> tiled bf16 hi/lo planes. Plane layout: [y(9)][kt(16)][r(128)][k(32)],
// tile rows 0-63 = magnitude pair rows, 64-127 = phase pair rows; zero-padded.
// ---------------------------------------------------------------------------
__global__ __launch_bounds__(256) void convert_B(
    const float* __restrict__ Wm, ushort_t* __restrict__ Bhi, ushort_t* __restrict__ Blo)
{
  const int gid = blockIdx.x * 256 + threadIdx.x;    // one 8-elem granule each
  if (gid >= 9*16*512) return;
  const int s  = gid & 3;
  const int r  = (gid >> 2) & 127;
  const int kt = (gid >> 9) & 15;
  const int y  = gid >> 13;
  int srow;
  if (r < 64) { int p = y*64 + r;        srow = (p < 513) ? p         : -1; }
  else        { int p = y*64 + (r - 64); srow = (p < 513) ? (513 + p) : -1; }
  float v[8];
  if (srow >= 0) {
    const float* src = Wm + (size_t)srow * 512 + kt*32 + s*8;
    const float4 a = *(const float4*)src;
    const float4 b = *(const float4*)(src + 4);
    v[0]=a.x; v[1]=a.y; v[2]=a.z; v[3]=a.w; v[4]=b.x; v[5]=b.y; v[6]=b.z; v[7]=b.w;
  } else {
    #pragma unroll
    for (int i = 0; i < 8; ++i) v[i] = 0.f;
  }
  uint32_t hi[4], lo[4];
  #pragma unroll
  for (int i = 0; i < 4; ++i) {
    const uint32_t b0 = __float_as_uint(v[2*i]), b1 = __float_as_uint(v[2*i+1]);
    hi[i] = (b0 >> 16) | (b1 & 0xFFFF0000u);
    const float f0 = v[2*i]   - __uint_as_float(b0 & 0xFFFF0000u);
    const float f1 = v[2*i+1] - __uint_as_float(b1 & 0xFFFF0000u);
    lo[i] = (__float_as_uint(f0) >> 16) | (__float_as_uint(f1) & 0xFFFF0000u);
  }
  const size_t off = (size_t)gid * 8;
  *(uint4*)(Bhi + off) = make_uint4(hi[0], hi[1], hi[2], hi[3]);
  *(uint4*)(Blo + off) = make_uint4(lo[0], lo[1], lo[2], lo[3]);
}

// ---------------------------------------------------------------------------
// K1: MFMA GEMM. Block = 128 rows x 64 column-pairs (128 spec cols), 4 waves,
// wave w owns rows 32w..32w+32 x all 128 cols (4 col-frags of 32x32).
// A staged f32 via global_load_lds (XOR-swizzled source), converted hi/lo at
// fragment read. B from pre-tiled bf16 planes. 3 MFMAs per (frag, k-half).
// ---------------------------------------------------------------------------
__global__ __launch_bounds__(256) void gemm_mfma(
    const float* __restrict__ hs, const ushort_t* __restrict__ Bhi,
    const ushort_t* __restrict__ Blo, const float* __restrict__ bias,
    float* __restrict__ coeffs)
{
  __shared__ float    Alds[128*32];   // 16KB, granule(r,sd)=16B, sd = s_logical ^ (r&7)
  __shared__ ushort_t Bh[128*32];     // 8KB,  sd = s_logical ^ ((r>>1)&3)
  __shared__ ushort_t Bl[128*32];     // 8KB

  const int tid = threadIdx.x;
  const int w = tid >> 6, l = tid & 63;
  // XCD-chunked swizzle over 2304 = 8 * 288 blocks; 9 consecutive y per mb.
  const int bid = blockIdx.x;
  const int swz = (bid & 7) * 288 + (bid >> 3);
  const int mb = swz / 9, y = swz - mb * 9;

  // staging source pointers
  const float* pa[4];
  #pragma unroll
  for (int j = 0; j < 4; ++j) {
    const int g = j*256 + tid;
    const int r = g >> 3, sd = g & 7;
    const int sl = sd ^ (r & 7);
    pa[j] = hs + (size_t)(mb*128 + r) * 512 + sl*4;
  }
  const ushort_t* pbh[2]; const ushort_t* pbl[2];
  #pragma unroll
  for (int j = 0; j < 2; ++j) {
    const int g = j*256 + tid;
    const int r = g >> 2, sd = g & 3;
    const int sl = sd ^ ((r >> 1) & 3);
    const size_t off = (size_t)y * (16*4096) + r*32 + sl*8;
    pbh[j] = Bhi + off; pbl[j] = Blo + off;
  }

  f32x16 acc[4];
  #pragma unroll
  for (int c = 0; c < 4; ++c)
    #pragma unroll
    for (int q = 0; q < 16; ++q) acc[c][q] = 0.f;

  const int lr = l & 31, lh = l >> 5;

#define STAGE(kt) do {                                                   \
    _Pragma("unroll")                                                    \
    for (int j = 0; j < 4; ++j)                                          \
      GLDS(pa[j] + (kt)*32, Alds + (j*256 + w*64)*4);                    \
    _Pragma("unroll")                                                    \
    for (int j = 0; j < 2; ++j) {                                        \
      GLDS(pbh[j] + (size_t)(kt)*4096, Bh + (j*256 + w*64)*8);           \
      GLDS(pbl[j] + (size_t)(kt)*4096, Bl + (j*256 + w*64)*8);           \
    }                                                                    \
  } while (0)

  STAGE(0);
  for (int kt = 0; kt < 16; ++kt) {
    __syncthreads();                 // staging (incl. vmcnt drain) complete
    #pragma unroll
    for (int kh = 0; kh < 2; ++kh) {
      bf16x8 fbh[4], fbl[4];
      #pragma unroll
      for (int cf = 0; cf < 4; ++cf) {
        const int r = cf*32 + lr;
        const int s = kh*2 + lh;
        const int sw = s ^ ((r >> 1) & 3);
        fbh[cf] = *(const bf16x8*)(Bh + r*32 + sw*8);
        fbl[cf] = *(const bf16x8*)(Bl + r*32 + sw*8);
      }
      const int ar = w*32 + lr;
      const int s0 = kh*4 + lh*2;
      const float4 a0 = *(const float4*)(Alds + ar*32 + ((s0    ) ^ (ar & 7))*4);
      const float4 a1 = *(const float4*)(Alds + ar*32 + ((s0 + 1) ^ (ar & 7))*4);
      const float av[8] = {a0.x,a0.y,a0.z,a0.w,a1.x,a1.y,a1.z,a1.w};
      union { uint32_t u[4]; bf16x8 v; } Ah, Al;
      #pragma unroll
      for (int i = 0; i < 4; ++i) {
        const uint32_t b0 = __float_as_uint(av[2*i]), b1 = __float_as_uint(av[2*i+1]);
        Ah.u[i] = (b0 >> 16) | (b1 & 0xFFFF0000u);
        const float f0 = av[2*i]   - __uint_as_float(b0 & 0xFFFF0000u);
        const float f1 = av[2*i+1] - __uint_as_float(b1 & 0xFFFF0000u);
        Al.u[i] = (__float_as_uint(f0) >> 16) | (__float_as_uint(f1) & 0xFFFF0000u);
      }
      #pragma unroll
      for (int cf = 0; cf < 4; ++cf) {
        acc[cf] = __builtin_amdgcn_mfma_f32_32x32x16_bf16(Ah.v, fbh[cf], acc[cf], 0, 0, 0);
        acc[cf] = __builtin_amdgcn_mfma_f32_32x32x16_bf16(Al.v, fbh[cf], acc[cf], 0, 0, 0);
        acc[cf] = __builtin_amdgcn_mfma_f32_32x32x16_bf16(Ah.v, fbl[cf], acc[cf], 0, 0, 0);
      }
    }
    __syncthreads();                 // everyone done reading before overwrite
    if (kt < 15) STAGE(kt + 1);
  }
#undef STAGE

  // Epilogue: mag frag m (cols 0-63) pairs with phase frag m+2 (cols 64-127),
  // identical lane->(row,col) maps. C/D: col=lane&31, row=(q&3)+8(q>>2)+4(l>>5).
  #pragma unroll
  for (int m = 0; m < 2; ++m) {
    const int p = y*64 + m*32 + lr;
    const int pc = (p < 513) ? p : 512;
    const float bm = bias[pc], bp = bias[513 + pc];
    const bool valid = (p < 513);
    #pragma unroll
    for (int q = 0; q < 16; ++q) {
      const int rl = (q & 3) + 8*(q >> 2) + 4*lh;
      const int f  = mb*128 + w*32 + rl;
      const float sm = acc[m][q] + bm;
      const float sp = acc[m+2][q] + bp;
      const float mag = fminf(__expf(sm), 100.0f);
      float aa = mag * __cosf(sp);
      float bb = mag * __sinf(sp);
      if (p == 0 || p == 512) bb = 0.f;
      if (valid) *(float2*)(coeffs + (size_t)f * RS + 2*p) = make_float2(aa, bb);
    }
  }
}

// ---------------------------------------------------------------------------
// K2: per-frame irfft(1024) + window (unchanged, verified).
// ---------------------------------------------------------------------------
#define PIDX(s) ((s) + ((s) >> 3))

template<int NS>
__device__ __forceinline__ void stage_fft(const float2* in, float2* out, int l)
{
  float2 v[8];
  #pragma unroll
  for (int r = 0; r < 8; ++r) v[r] = in[PIDX(l + 64*r)];
  if (NS > 1) {
    const float ang = TWO_PI * (float)(l & (NS-1)) / (float)(NS * 8);
    float sn, cs; __sincosf(ang, &sn, &cs);
    const float2 wb = f2(cs, sn);
    float2 cur = wb;
    #pragma unroll
    for (int r = 1; r < 8; ++r) { v[r] = cmul(v[r], cur); cur = cmul(cur, wb); }
  }
  const float2 e0=v[0], e1=v[2], e2=v[4], e3=v[6];
  const float2 o0=v[1], o1=v[3], o2=v[5], o3=v[7];
  float2 a = cadd(e0,e2), b = csub(e0,e2), c = cadd(e1,e3), d = csub(e1,e3);
  const float2 E0 = cadd(a,c), E2 = csub(a,c);
  const float2 E1 = f2(b.x - d.y, b.y + d.x), E3 = f2(b.x + d.y, b.y - d.x);
  a = cadd(o0,o2); b = csub(o0,o2); c = cadd(o1,o3); d = csub(o1,o3);
  const float2 O0 = cadd(a,c), O2 = csub(a,c);
  const float2 O1 = f2(b.x - d.y, b.y + d.x), O3 = f2(b.x + d.y, b.y - d.x);
  const float r2 = 0.70710678118654752f;
  const float2 t0 = O0;
  const float2 t1 = f2(r2*(O1.x - O1.y),  r2*(O1.x + O1.y));
  const float2 t2 = f2(-O2.y, O2.x);
  const float2 t3 = f2(-r2*(O3.x + O3.y), r2*(O3.x - O3.y));
  float2 X[8];
  X[0]=cadd(E0,t0); X[4]=csub(E0,t0);
  X[1]=cadd(E1,t1); X[5]=csub(E1,t1);
  X[2]=cadd(E2,t2); X[6]=csub(E2,t2);
  X[3]=cadd(E3,t3); X[7]=csub(E3,t3);
  const int idxD = (l / NS) * (NS * 8) + (l & (NS-1));
  #pragma unroll
  for (int q = 0; q < 8; ++q) out[PIDX(idxD + q*NS)] = X[q];
}

__global__ __launch_bounds__(256) void fft_win(
    const float* coeffs, float* frames, const float* __restrict__ window)
{
  __shared__ float2 bA[4][576];
  __shared__ float2 bB[4][576];
  const int tid = threadIdx.x;
  const int w = tid >> 6, l = tid & 63;
  const size_t f = (size_t)blockIdx.x * 4 + w;
  const float* crow = coeffs + f * RS;
  const float sc = 1.0f / 1024.0f;
  const float a512 = crow[1024];

  #pragma unroll
  for (int j = 0; j < 4; ++j) {
    const int k = 1 + l + 64*j;
    const float2 Ck = *(const float2*)(crow + 2*k);
    const float2 Cq = *(const float2*)(crow + 2*(512-k));
    float sn, cs; __sincosf(TWO_PI * (1.0f/1024.0f) * (float)k, &sn, &cs);
    const float Ex = sc*(Ck.x + Cq.x), Ey = sc*(Ck.y - Cq.y);
    const float Dx = Ck.x - Cq.x,      Dy = Ck.y + Cq.y;
    const float Ox = sc*(cs*Dx - sn*Dy), Oy = sc*(cs*Dy + sn*Dx);
    bA[w][PIDX(k)]     = f2(Ex - Oy, Ey + Ox);
    bA[w][PIDX(512-k)] = f2(Ex + Oy, Ox - Ey);
  }
  if (l == 0) {
    const float a0 = crow[0];
    bA[w][PIDX(0)] = f2(sc*(a0 + a512), sc*(a0 - a512));
  }
  __syncthreads();
  stage_fft<1 >(bA[w], bB[w], l);
  __syncthreads();
  stage_fft<8 >(bB[w], bA[w], l);
  __syncthreads();
  stage_fft<64>(bA[w], bB[w], l);
  __syncthreads();

  float* frow = frames + f * RS;
  #pragma unroll
  for (int j = 0; j < 8; ++j) {
    const int m = l + 64*j;
    const float2 z  = bB[w][PIDX(m)];
    const float2 wv = *(const float2*)(window + 2*m);
    *(float2*)(frow + 2*m) = f2(z.x * wv.x, z.y * wv.y);
  }
}

// ---------------------------------------------------------------------------
// K3: overlap-add gather + normalization (unchanged, verified).
// ---------------------------------------------------------------------------
__global__ __launch_bounds__(256) void gather_out(
    const float* __restrict__ frames, const float* __restrict__ window,
    float* __restrict__ out)
{
  const int idx = blockIdx.x * 256 + threadIdx.x;
  const int b  = idx >> 19;
  const int jj = idx & 524287;
  const int s  = jj + 384;
  int tlo = (s - 768) >> 8; if (tlo < 0) tlo = 0;
  int thi = s >> 8;         if (thi > 2047) thi = 2047;
  float acc = 0.f, nrm = 0.f;
  for (int t = tlo; t <= thi; ++t) {
    const int n = s - (t << 8);
    const float wv = window[n];
    nrm = fmaf(wv, wv, nrm);
    acc += frames[(size_t)(b * 2048 + t) * RS + n];
  }
  out[idx] = acc / nrm;
}

// ---------------------------------------------------------------------------
extern "C" void kernel_launch(void* const* d_in, const int* in_sizes, int n_in,
                              void* d_out, int out_size, void* d_ws, size_t ws_size,
                              hipStream_t stream)
{
  const float* hs     = (const float*)d_in[0];   // (16,2048,512)
  const float* Wm     = (const float*)d_in[1];   // (1026,512)
  const float* bias   = (const float*)d_in[2];   // (1026,)
  const float* window = (const float*)d_in[3];   // (1024,)

  float* buf = (float*)d_ws;                                   // 134,742,016 B
  ushort_t* Bhi = (ushort_t*)((char*)d_ws + 134742016);        // 1,179,648 B
  ushort_t* Blo = Bhi + 9*16*4096;                             // 1,179,648 B

  convert_B<<<288, 256, 0, stream>>>(Wm, Bhi, Blo);
  gemm_mfma<<<2304, 256, 0, stream>>>(hs, Bhi, Blo, bias, buf);
  fft_win<<<FRAMES / 4, 256, 0, stream>>>(buf, buf, window);
  gather_out<<<8388608 / 256, 256, 0, stream>>>(buf, window, (float*)d_out);
}